// Round 11
// baseline (147.687 us; speedup 1.0000x reference)
//
#include <hip/hip_runtime.h>

#define NB 8
#define NT 2048
#define NC 1024
#define NH 64
#define BT (NB*NT)

typedef __bf16 bf16x8 __attribute__((ext_vector_type(8)));
typedef float  f32x4  __attribute__((ext_vector_type(4)));
typedef unsigned short us8 __attribute__((ext_vector_type(8)));

__device__ __forceinline__ unsigned short f2bf(float f) {
  unsigned u = __builtin_bit_cast(unsigned, f);
  u = (u + 0x7FFFu + ((u >> 16) & 1u)) >> 16;   // RNE
  return (unsigned short)u;
}

__device__ __forceinline__ bf16x8 ld_frag(const unsigned short* p) {
  return __builtin_bit_cast(bf16x8, *(const us8*)p);
}

// ---------------------------------------------------------------------------
// Kernel 0: W -> bf16 transposed Wt[192][1024] (row = mat*64+h; 0:q 1:k 2:v).
// ---------------------------------------------------------------------------
__global__ __launch_bounds__(256) void wconv_kernel(
    const float* __restrict__ Wk, const float* __restrict__ Wq,
    const float* __restrict__ Wv, unsigned short* __restrict__ Wt)
{
  __shared__ unsigned short T[64][72];
  const int t = threadIdx.x;
  const int mat = blockIdx.x >> 4;
  const int k0 = (blockIdx.x & 15) * 64;
  const float* __restrict__ W = (mat == 0) ? Wq : (mat == 1) ? Wk : Wv;
  const int kk = t >> 2, h0 = (t & 3) * 16;
  const float* src = &W[(size_t)(k0 + kk) * NH + h0];
#pragma unroll
  for (int j = 0; j < 4; ++j) {
    const float4 v = *(const float4*)(src + j*4);
    T[h0 + j*4 + 0][kk] = f2bf(v.x);
    T[h0 + j*4 + 1][kk] = f2bf(v.y);
    T[h0 + j*4 + 2][kk] = f2bf(v.z);
    T[h0 + j*4 + 3][kk] = f2bf(v.w);
  }
  __syncthreads();
  const int h = t >> 2, c0 = (t & 3) * 16;
  unsigned short* dst = &Wt[(size_t)(mat*64 + h) * NC + k0 + c0];
  *(us8*)dst       = *(const us8*)&T[h][c0];
  *(us8*)(dst + 8) = *(const us8*)&T[h][c0 + 8];
}

// ---------------------------------------------------------------------------
// Kernel 1: fused QKV projection (unchanged from round 10).
// ---------------------------------------------------------------------------
__global__ __launch_bounds__(256) void proj_kernel(
    const float* __restrict__ x, const unsigned short* __restrict__ Wt,
    unsigned short* __restrict__ qkv)
{
  __shared__ float Asmf[2][32][68];            // [buf][row][k] f32, +4 pad
  __shared__ unsigned short Bsm[2][192][72];   // [buf][col'][k] bf16, +8 pad
  __shared__ unsigned short Vb[64][40];        // v-transpose buffer

  const int t = threadIdx.x, w = t >> 6, lane = t & 63;
  const int m0 = blockIdx.x * 32;
  const int fr = lane & 15, fo = (lane >> 4) * 8, rg = (lane >> 4) * 4;

  f32x4 acc[2][3];
#pragma unroll
  for (int m = 0; m < 2; ++m)
#pragma unroll
    for (int n = 0; n < 3; ++n) acc[m][n] = (f32x4){0.f, 0.f, 0.f, 0.f};

  const int srow0 = t >> 4, scol = (t & 15) * 4;
  const int srow1 = srow0 + 16;

  {
    const float4 a = *(const float4*)&x[(size_t)(m0 + srow0) * NC + scol];
    const float4 b = *(const float4*)&x[(size_t)(m0 + srow1) * NC + scol];
    *(f32x4*)&Asmf[0][srow0][scol] = (f32x4){a.x, a.y, a.z, a.w};
    *(f32x4*)&Asmf[0][srow1][scol] = (f32x4){b.x, b.y, b.z, b.w};
#pragma unroll
    for (int i = 0; i < 6; ++i) {
      const int c = t + 256*i, rr = c >> 3, kc = (c & 7) * 8;
      *(us8*)&Bsm[0][rr][kc] = *(const us8*)&Wt[(size_t)rr * NC + kc];
    }
  }
  __syncthreads();

  for (int s = 0; s < 16; ++s) {
    const int cur = s & 1;
    if (s < 15) {
      const int k1 = (s + 1) * 64;
      const float4 a = *(const float4*)&x[(size_t)(m0 + srow0) * NC + k1 + scol];
      const float4 b = *(const float4*)&x[(size_t)(m0 + srow1) * NC + k1 + scol];
      *(f32x4*)&Asmf[cur^1][srow0][scol] = (f32x4){a.x, a.y, a.z, a.w};
      *(f32x4*)&Asmf[cur^1][srow1][scol] = (f32x4){b.x, b.y, b.z, b.w};
#pragma unroll
      for (int i = 0; i < 6; ++i) {
        const int c = t + 256*i, rr = c >> 3, kc = (c & 7) * 8;
        *(us8*)&Bsm[cur^1][rr][kc] = *(const us8*)&Wt[(size_t)rr * NC + k1 + kc];
      }
    }

    bf16x8 af[2][2], bfr[2][3];
#pragma unroll
    for (int m = 0; m < 2; ++m)
#pragma unroll
      for (int ks = 0; ks < 2; ++ks) {
        const f32x4 lo = *(const f32x4*)&Asmf[cur][m*16 + fr][ks*32 + fo];
        const f32x4 hi = *(const f32x4*)&Asmf[cur][m*16 + fr][ks*32 + fo + 4];
        bf16x8 v;
        v[0] = (__bf16)lo[0]; v[1] = (__bf16)lo[1]; v[2] = (__bf16)lo[2]; v[3] = (__bf16)lo[3];
        v[4] = (__bf16)hi[0]; v[5] = (__bf16)hi[1]; v[6] = (__bf16)hi[2]; v[7] = (__bf16)hi[3];
        af[m][ks] = v;
      }
#pragma unroll
    for (int ks = 0; ks < 2; ++ks)
#pragma unroll
      for (int n = 0; n < 3; ++n)
        bfr[ks][n] = ld_frag(&Bsm[cur][w*48 + n*16 + fr][ks*32 + fo]);
#pragma unroll
    for (int ks = 0; ks < 2; ++ks)
#pragma unroll
      for (int m = 0; m < 2; ++m)
#pragma unroll
        for (int n = 0; n < 3; ++n)
          acc[m][n] = __builtin_amdgcn_mfma_f32_16x16x32_bf16(af[m][ks], bfr[ks][n], acc[m][n], 0, 0, 0);
    __syncthreads();
  }

#pragma unroll
  for (int m = 0; m < 2; ++m)
#pragma unroll
    for (int n = 0; n < 3; ++n) {
      const int col = w*48 + n*16;
      if (col < 128) {
        unsigned short* op = qkv + (size_t)(col >> 6) * BT * NH;
        const int h = (col & 63) + fr;
#pragma unroll
        for (int r = 0; r < 4; ++r)
          op[(size_t)(m0 + m*16 + rg + r) * NH + h] = f2bf(acc[m][n][r]);
      } else {
#pragma unroll
        for (int r = 0; r < 4; ++r)
          Vb[(col - 128) + fr][m*16 + rg + r] = f2bf(acc[m][n][r]);
      }
    }
  __syncthreads();
  {
    unsigned short* vt = qkv + (size_t)2 * BT * NH;
    const int h = t >> 2, c = (t & 3) * 8;
    *(us8*)&vt[(size_t)h * BT + m0 + c] = *(const us8*)&Vb[h][c];
  }
}

// ---------------------------------------------------------------------------
// Kernel 2: causal attention, wave-private LDS pipeline.
// 8 waves = 2 rowgroups(16 q-rows) x 4 kv-parts; KVBLK=32. Each wave stages
// its own K (natural [kv][h]) and vT ([h][kv]) tile into private LDS with
// coalesced 1KB loads; next tile's loads prefetch into registers during
// compute (T14). NO barriers in the kv loop (wave-private DS, lgkmcnt-
// ordered). Phases (j, 63-j) of 32 q-rows -> uniform 65 tiles/block.
// Fixed-offset softmax p=exp(s/8). Grid (32,8)=256 blocks x 512 thr.
// ---------------------------------------------------------------------------
__global__ __launch_bounds__(512) void attn_kernel(
    const unsigned short* __restrict__ qkv, float* __restrict__ out)
{
  __shared__ unsigned short Ksm[8][32][72];   // per-wave K tile [kv][h], +8 pad
  __shared__ unsigned short Vsm[8][64][36];   // per-wave vT tile [h][kv], +4 pad
  __shared__ unsigned short Psm[8][16][36];   // per-wave P tile [qrow][kv]
  __shared__ float co[8][16][68];             // partial O per wave
  __shared__ float cl[8][16];                 // partial denom per wave

  const int t = threadIdx.x, w = t >> 6, lane = t & 63;
  const int b = blockIdx.y;
  const int j0 = blockIdx.x;                  // 0..31
  const int g = w & 1, p = w >> 1;            // rowgroup, kv-part
  const unsigned short* __restrict__ qp = qkv;
  const unsigned short* __restrict__ kp = qkv + (size_t)BT * NH;
  const unsigned short* __restrict__ vt = qkv + (size_t)2 * BT * NH;
  const int fr = lane & 15, fo = (lane >> 4) * 8, rg = (lane >> 4) * 4;
  const int krow = lane >> 3, kcol = (lane & 7) * 8;   // K stage: 8 rows x 128B
  const int vrow = lane >> 2, vcol = (lane & 3) * 8;   // V stage: 16 rows x 64B

#pragma unroll 1
  for (int ph = 0; ph < 2; ++ph) {
    const int j = ph ? (63 - j0) : j0;
    const int ntiles = j + 1;                 // 32-wide kv tiles
    const int q0 = j*32 + g*16;

    bf16x8 aq0, aq1;
    {
      const size_t qoff = ((size_t)b * NT + q0 + fr) * NH;
      aq0 = ld_frag(&qp[qoff + fo]);
      aq1 = ld_frag(&qp[qoff + 32 + fo]);
    }

    f32x4 o[4];
#pragma unroll
    for (int n = 0; n < 4; ++n) o[n] = (f32x4){0.f, 0.f, 0.f, 0.f};
    float lp[4] = {0.f, 0.f, 0.f, 0.f};

    us8 kreg[4], vreg[4];
    { // prologue: load this wave's first tile into registers
      const int kt0 = (p < ntiles) ? p : (ntiles - 1);
      const size_t kb = (size_t)b * NT + kt0 * 32;
#pragma unroll
      for (int i = 0; i < 4; ++i)
        kreg[i] = *(const us8*)&kp[(kb + i*8 + krow) * NH + kcol];
#pragma unroll
      for (int i = 0; i < 4; ++i)
        vreg[i] = *(const us8*)&vt[(size_t)(i*16 + vrow) * BT + kb + vcol];
    }

    for (int kt = p; kt < ntiles; kt += 4) {
      const int kv0 = kt * 32;
      // write staged tile to wave-private LDS
#pragma unroll
      for (int i = 0; i < 4; ++i)
        *(us8*)&Ksm[w][i*8 + krow][kcol] = kreg[i];
#pragma unroll
      for (int i = 0; i < 4; ++i)
        *(us8*)&Vsm[w][i*16 + vrow][vcol] = vreg[i];

      { // prefetch next tile into registers (latency hides under compute)
        const int nk = (kt + 4 < ntiles) ? kt + 4 : kt;
        const size_t kb = (size_t)b * NT + nk * 32;
#pragma unroll
        for (int i = 0; i < 4; ++i)
          kreg[i] = *(const us8*)&kp[(kb + i*8 + krow) * NH + kcol];
#pragma unroll
        for (int i = 0; i < 4; ++i)
          vreg[i] = *(const us8*)&vt[(size_t)(i*16 + vrow) * BT + kb + vcol];
      }

      // S = q @ k^T from LDS (b128, ~2-way max conflict)
      f32x4 s[2];
#pragma unroll
      for (int n = 0; n < 2; ++n) s[n] = (f32x4){0.f, 0.f, 0.f, 0.f};
#pragma unroll
      for (int n = 0; n < 2; ++n) {
        bf16x8 k0 = ld_frag(&Ksm[w][n*16 + fr][fo]);
        bf16x8 k1 = ld_frag(&Ksm[w][n*16 + fr][32 + fo]);
        s[n] = __builtin_amdgcn_mfma_f32_16x16x32_bf16(aq0, k0, s[n], 0, 0, 0);
        s[n] = __builtin_amdgcn_mfma_f32_16x16x32_bf16(aq1, k1, s[n], 0, 0, 0);
      }

#pragma unroll
      for (int n = 0; n < 2; ++n)
#pragma unroll
        for (int r = 0; r < 4; ++r) s[n][r] = __expf(s[n][r] * 0.125f);

      if (kt == ntiles - 1) {   // only the last tile is causally partial
#pragma unroll
        for (int n = 0; n < 2; ++n) {
          const int col = kv0 + n*16 + fr;
#pragma unroll
          for (int r = 0; r < 4; ++r)
            if (col > q0 + rg + r) s[n][r] = 0.f;
        }
      }

#pragma unroll
      for (int r = 0; r < 4; ++r) lp[r] += s[0][r] + s[1][r];

      // P -> per-wave LDS (C-layout), read back in A-layout (same wave)
#pragma unroll
      for (int n = 0; n < 2; ++n)
#pragma unroll
        for (int r = 0; r < 4; ++r)
          Psm[w][rg + r][n*16 + fr] = f2bf(s[n][r]);

      bf16x8 pa = ld_frag(&Psm[w][fr][fo]);
#pragma unroll
      for (int n = 0; n < 4; ++n) {
        bf16x8 bv = ld_frag(&Vsm[w][n*16 + fr][fo]);
        o[n] = __builtin_amdgcn_mfma_f32_16x16x32_bf16(pa, bv, o[n], 0, 0, 0);
      }
    }

    // publish per-wave partials
#pragma unroll
    for (int r = 0; r < 4; ++r) {
#pragma unroll
      for (int off = 1; off < 16; off <<= 1) lp[r] += __shfl_xor(lp[r], off);
    }
    if (fr == 0) {
#pragma unroll
      for (int r = 0; r < 4; ++r) cl[w][rg + r] = lp[r];
    }
#pragma unroll
    for (int n = 0; n < 4; ++n)
#pragma unroll
      for (int r = 0; r < 4; ++r) co[w][rg + r][n*16 + fr] = o[n][r];
    __syncthreads();

    { // merge 4 kv-parts per rowgroup: plain sums (common exponent offset)
      const int row = t >> 4, c0 = (t & 15) * 4;    // row 0..31
      const int g2 = row >> 4, rr = row & 15;
      const float l = (cl[g2][rr] + cl[2 + g2][rr]) + (cl[4 + g2][rr] + cl[6 + g2][rr]);
      const float inv = 1.f / l;
      float4 ov;
      ov.x = ((co[g2][rr][c0+0] + co[2+g2][rr][c0+0]) + (co[4+g2][rr][c0+0] + co[6+g2][rr][c0+0])) * inv;
      ov.y = ((co[g2][rr][c0+1] + co[2+g2][rr][c0+1]) + (co[4+g2][rr][c0+1] + co[6+g2][rr][c0+1])) * inv;
      ov.z = ((co[g2][rr][c0+2] + co[2+g2][rr][c0+2]) + (co[4+g2][rr][c0+2] + co[6+g2][rr][c0+2])) * inv;
      ov.w = ((co[g2][rr][c0+3] + co[2+g2][rr][c0+3]) + (co[4+g2][rr][c0+3] + co[6+g2][rr][c0+3])) * inv;
      *(float4*)&out[((size_t)b*NT + j*32 + row) * NH + c0] = ov;
    }
    if (ph == 0) __syncthreads();
  }
}

extern "C" void kernel_launch(void* const* d_in, const int* in_sizes, int n_in,
                              void* d_out, int out_size, void* d_ws, size_t ws_size,
                              hipStream_t stream) {
  (void)in_sizes; (void)n_in; (void)out_size; (void)ws_size;
  const float* x  = (const float*)d_in[0];
  const float* Wk = (const float*)d_in[1];
  const float* Wq = (const float*)d_in[2];
  const float* Wv = (const float*)d_in[3];
  unsigned short* qkv = (unsigned short*)d_ws;                       // q,k natural + vT, 6 MB
  unsigned short* Wt  = qkv + (size_t)3 * BT * NH;                   // 384 KB

  wconv_kernel<<<48, 256, 0, stream>>>(Wk, Wq, Wv, Wt);
  proj_kernel<<<BT/32, 256, 0, stream>>>(x, Wt, qkv);
  attn_kernel<<<dim3(32, NB), 512, 0, stream>>>(qkv, (float*)d_out);
}